// Round 1
// baseline (704.900 us; speedup 1.0000x reference)
//
#include <hip/hip_runtime.h>

#define NN 100000   // nodes
#define NE 3200000  // edges
#define NF 512      // in features
#define NH 16       // hidden
#define NC 7        // classes

// ---------------------------------------------------------------------------
// GEMM1: h0[n, 0:16] = x[n, 0:512] @ W1[512,16].  One wave per row.
// Each lane owns k in {4*lane..4*lane+3, 256+4*lane..256+4*lane+3}; W1 rows
// for those k live in registers (128 VGPRs), loaded once per wave.
// ---------------------------------------------------------------------------
__global__ __launch_bounds__(256) void gemm1_kernel(const float* __restrict__ x,
                                                    const float* __restrict__ W1,
                                                    float* __restrict__ h0) {
  const int lane = threadIdx.x & 63;
  const int wave = (blockIdx.x * blockDim.x + threadIdx.x) >> 6;
  const int nwaves = (gridDim.x * blockDim.x) >> 6;

  float w[8][NH];
#pragma unroll
  for (int i = 0; i < 4; ++i) {
#pragma unroll
    for (int j = 0; j < NH; ++j) {
      w[i][j]     = W1[(4 * lane + i) * NH + j];
      w[4 + i][j] = W1[(256 + 4 * lane + i) * NH + j];
    }
  }

  for (int row = wave; row < NN; row += nwaves) {
    const float4* xr = (const float4*)(x + (size_t)row * NF);
    float4 a0 = xr[lane];        // k = 4*lane .. 4*lane+3
    float4 a1 = xr[64 + lane];   // k = 256+4*lane ..
    float a[8] = {a0.x, a0.y, a0.z, a0.w, a1.x, a1.y, a1.z, a1.w};

    float acc[NH];
#pragma unroll
    for (int j = 0; j < NH; ++j) acc[j] = 0.f;
#pragma unroll
    for (int i = 0; i < 8; ++i) {
#pragma unroll
      for (int j = 0; j < NH; ++j) acc[j] += a[i] * w[i][j];
    }

    float outv = 0.f;
#pragma unroll
    for (int j = 0; j < NH; ++j) {
      float v = acc[j];
      v += __shfl_xor(v, 1);
      v += __shfl_xor(v, 2);
      v += __shfl_xor(v, 4);
      v += __shfl_xor(v, 8);
      v += __shfl_xor(v, 16);
      v += __shfl_xor(v, 32);
      if (lane == j) outv = v;   // lane j keeps column j's full sum
    }
    if (lane < NH) h0[(size_t)row * NH + lane] = outv;
  }
}

// ---------------------------------------------------------------------------
// Scatter layer 1: agg1[dst,j] += h0[src,j].  16 lanes per edge (j = gid&15).
// ---------------------------------------------------------------------------
__global__ __launch_bounds__(256) void scatter16_kernel(const int* __restrict__ ei,
                                                        const float* __restrict__ h0,
                                                        float* __restrict__ agg) {
  long long gid = (long long)blockIdx.x * blockDim.x + threadIdx.x;
  int e = (int)(gid >> 4);
  if (e >= NE) return;
  int j = (int)(gid & 15);
  int s = ei[e];
  int d = ei[NE + e];
  atomicAdd(&agg[(size_t)d * NH + j], h0[(size_t)s * NH + j]);
}

// ---------------------------------------------------------------------------
// Per-node transform: p[n, 0:7] = relu(agg1[n] + b1) @ W2, p stride 8.
// ---------------------------------------------------------------------------
__global__ __launch_bounds__(256) void transform_kernel(const float* __restrict__ agg1,
                                                        const float* __restrict__ b1,
                                                        const float* __restrict__ W2,
                                                        float* __restrict__ p) {
  int n = blockIdx.x * blockDim.x + threadIdx.x;
  if (n >= NN) return;
  const float4* r = (const float4*)(agg1 + (size_t)n * NH);
  float4 v0 = r[0], v1 = r[1], v2 = r[2], v3 = r[3];
  float h[NH] = {v0.x, v0.y, v0.z, v0.w, v1.x, v1.y, v1.z, v1.w,
                 v2.x, v2.y, v2.z, v2.w, v3.x, v3.y, v3.z, v3.w};
#pragma unroll
  for (int k = 0; k < NH; ++k) h[k] = fmaxf(h[k] + b1[k], 0.f);

#pragma unroll
  for (int j = 0; j < NC; ++j) {
    float acc = 0.f;
#pragma unroll
    for (int k = 0; k < NH; ++k) acc += h[k] * W2[k * NC + j];
    p[(size_t)n * 8 + j] = acc;
  }
}

// ---------------------------------------------------------------------------
// Scatter layer 2: agg2[dst,j] += p[src,j].  8 lanes per edge, lane 7 idle.
// agg2 stride 8.
// ---------------------------------------------------------------------------
__global__ __launch_bounds__(256) void scatter7_kernel(const int* __restrict__ ei,
                                                       const float* __restrict__ p,
                                                       float* __restrict__ agg) {
  long long gid = (long long)blockIdx.x * blockDim.x + threadIdx.x;
  int e = (int)(gid >> 3);
  if (e >= NE) return;
  int j = (int)(gid & 7);
  if (j >= NC) return;
  int s = ei[e];
  int d = ei[NE + e];
  atomicAdd(&agg[(size_t)d * 8 + j], p[(size_t)s * 8 + j]);
}

// ---------------------------------------------------------------------------
// log_softmax over 7 classes; agg2 stride 8 in, out stride 7.
// ---------------------------------------------------------------------------
__global__ __launch_bounds__(256) void lsm_kernel(const float* __restrict__ agg2,
                                                  const float* __restrict__ b2,
                                                  float* __restrict__ out) {
  int n = blockIdx.x * blockDim.x + threadIdx.x;
  if (n >= NN) return;
  float z[NC];
  float m = -1e30f;
#pragma unroll
  for (int j = 0; j < NC; ++j) {
    z[j] = agg2[(size_t)n * 8 + j] + b2[j];
    m = fmaxf(m, z[j]);
  }
  float s = 0.f;
#pragma unroll
  for (int j = 0; j < NC; ++j) s += __expf(z[j] - m);
  float l = __logf(s);
#pragma unroll
  for (int j = 0; j < NC; ++j) out[(size_t)n * NC + j] = z[j] - m - l;
}

extern "C" void kernel_launch(void* const* d_in, const int* in_sizes, int n_in,
                              void* d_out, int out_size, void* d_ws, size_t ws_size,
                              hipStream_t stream) {
  const float* x  = (const float*)d_in[0];
  const int*   ei = (const int*)d_in[1];   // [2, NE] int32: src row then dst row
  const float* W1 = (const float*)d_in[2];
  const float* b1 = (const float*)d_in[3];
  const float* W2 = (const float*)d_in[4];
  const float* b2 = (const float*)d_in[5];
  float* out = (float*)d_out;

  // ws layout (12.8 MB): bufA = h0[NN*16] then p[NN*8]; bufB = agg1[NN*16] then agg2[NN*8]
  float* bufA = (float*)d_ws;
  float* bufB = bufA + (size_t)NN * NH;

  hipMemsetAsync(bufB, 0, (size_t)NN * NH * sizeof(float), stream);
  gemm1_kernel<<<2048, 256, 0, stream>>>(x, W1, bufA);
  scatter16_kernel<<<(int)(((long long)NE * 16 + 255) / 256), 256, 0, stream>>>(ei, bufA, bufB);
  transform_kernel<<<(NN + 255) / 256, 256, 0, stream>>>(bufB, b1, W2, bufA);
  hipMemsetAsync(bufB, 0, (size_t)NN * 8 * sizeof(float), stream);
  scatter7_kernel<<<(int)(((long long)NE * 8 + 255) / 256), 256, 0, stream>>>(ei, bufA, bufB);
  lsm_kernel<<<(NN + 255) / 256, 256, 0, stream>>>(bufB, b2, out);
}